// Round 5
// baseline (340.180 us; speedup 1.0000x reference)
//
#include <hip/hip_runtime.h>
#include <hip/hip_fp16.h>

// Clang-native vector types (__builtin_nontemporal_load rejects HIP_vector_type).
typedef float    vfloat4 __attribute__((ext_vector_type(4)));
typedef int      vint4   __attribute__((ext_vector_type(4)));
typedef _Float16 vhalf4  __attribute__((ext_vector_type(4)));

// Bypass gather: agent-scope relaxed atomic load -> sc0, skips L1 (no 64B line
// fill), request+return go straight to the L2 path.
__device__ __forceinline__ float gather_bypass(const unsigned short* tbl, int idx) {
    unsigned short raw = __hip_atomic_load(&tbl[idx], __ATOMIC_RELAXED,
                                           __HIP_MEMORY_SCOPE_AGENT);
    return (float)__builtin_bit_cast(_Float16, raw);
}
// Normal cached gather: goes through L1/TCP MSHR path.
__device__ __forceinline__ float gather_l1(const unsigned short* tbl, int idx) {
    return (float)__builtin_bit_cast(_Float16, tbl[idx]);
}

// Phase 1 (fused): values_h = fp16(pred*(ub-lb)+lb); zero ax; zero out.
__global__ void denorm_zero_kernel(const vfloat4* __restrict__ pred,
                                   const vfloat4* __restrict__ lb,
                                   const vfloat4* __restrict__ ub,
                                   vhalf4* __restrict__ values_h,
                                   vfloat4* __restrict__ ax,
                                   float* __restrict__ out,
                                   int n4v, int n4c) {
    int i = blockIdx.x * blockDim.x + threadIdx.x;
    if (i < n4v) {
        vfloat4 p = pred[i], l = lb[i], u = ub[i];
        vhalf4 h;
        h.x = (_Float16)fmaf(p.x, u.x - l.x, l.x);
        h.y = (_Float16)fmaf(p.y, u.y - l.y, l.y);
        h.z = (_Float16)fmaf(p.z, u.z - l.z, l.z);
        h.w = (_Float16)fmaf(p.w, u.w - l.w, l.w);
        values_h[i] = h;
    }
    if (i < n4c) {
        vfloat4 z = {0.f, 0.f, 0.f, 0.f};
        ax[i] = z;
    }
    if (i == 0) *out = 0.0f;
}

// Phase 2: thread-coarsened segmented sum, DIRECT global atomics (R4: LDS
// window removal was +3%, kept for simplicity).
// CHANGE (R5): K=16 -> K=32. Each thread now has 56 VMEM ops in flight
// (8 vidx + 8 cidx + 32 gathers + 8 coeff) before the consume loop.
// __launch_bounds__(256,4) caps VGPR at 128 (peak live ~110 by liveness
// math: vix dies progressively as gathers issue) -> 16 waves/CU x 56 =
// ~900 in-flight VMEM/CU vs previous ~550. Decisive MLP-vs-service-rate
// experiment: identical request count and pattern, only concurrency doubles.
// Streams stay nontemporal dwordx4 via L2 (R1: L3-direct -39%); gather mix
// 25/75 L1/bypass (R2: insensitive).
__global__ void __launch_bounds__(256, 4)
scatter_kernel(const vfloat4* __restrict__ coeff,
               const vint4* __restrict__ cidx,
               const vint4* __restrict__ vidx,
               const unsigned short* __restrict__ values,
               float* __restrict__ ax,
               int nnz) {
    const int K = 32;
    long base = ((long)blockIdx.x * 256 + threadIdx.x) * K;
    if (base >= nnz) return;

    if (base + K <= nnz) {
        long b4 = base / 4;
        int cseg[32]; int vix[32]; float cf[32]; float vals[32];
        // vidx first: the gathers depend on it, start that wait earliest.
        #pragma unroll
        for (int j = 0; j < 8; j++) {
            vint4 v = __builtin_nontemporal_load(&vidx[b4 + j]);
            vix[4*j+0] = v.x; vix[4*j+1] = v.y; vix[4*j+2] = v.z; vix[4*j+3] = v.w;
        }
        #pragma unroll
        for (int j = 0; j < 8; j++) {
            vint4 c = __builtin_nontemporal_load(&cidx[b4 + j]);
            cseg[4*j+0] = c.x; cseg[4*j+1] = c.y; cseg[4*j+2] = c.z; cseg[4*j+3] = c.w;
        }
        // 25/75 L1/bypass gather mix; vix[k] dies as each gather issues.
        #pragma unroll
        for (int k = 0; k < 32; k += 4) {
            vals[k]     = gather_l1(values, vix[k]);         // L1/MSHR path
            vals[k + 1] = gather_bypass(values, vix[k + 1]); // sc0/L2 path
            vals[k + 2] = gather_bypass(values, vix[k + 2]);
            vals[k + 3] = gather_bypass(values, vix[k + 3]);
        }
        #pragma unroll
        for (int j = 0; j < 8; j++) {
            vfloat4 f = __builtin_nontemporal_load(&coeff[b4 + j]);
            cf[4*j+0] = f.x; cf[4*j+1] = f.y; cf[4*j+2] = f.z; cf[4*j+3] = f.w;
        }

        int cur = cseg[0];
        float acc = cf[0] * vals[0];
        #pragma unroll
        for (int k = 1; k < 32; k++) {
            if (cseg[k] == cur) {
                acc = fmaf(cf[k], vals[k], acc);
            } else {
                atomicAdd(&ax[cur], acc);
                cur = cseg[k];
                acc = cf[k] * vals[k];
            }
        }
        atomicAdd(&ax[cur], acc);
    } else {
        // Tail chunk: scalar.
        const int* ci = (const int*)cidx;
        const int* vi = (const int*)vidx;
        const float* cf = (const float*)coeff;
        int cur = ci[base];
        float acc = cf[base] * gather_bypass(values, vi[base]);
        for (long k = base + 1; k < nnz; k++) {
            int s = ci[k];
            float p = cf[k] * gather_bypass(values, vi[k]);
            if (s == cur) acc += p;
            else {
                atomicAdd(&ax[cur], acc);
                cur = s; acc = p;
            }
        }
        atomicAdd(&ax[cur], acc);
    }
}

// Phase 3: violations by sense (x4 vectorized), block reduce, one atomic.
__global__ void violation_kernel(const vfloat4* __restrict__ ax,
                                 const vfloat4* __restrict__ rhs,
                                 const vint4* __restrict__ sense,
                                 float* __restrict__ out,
                                 int n4, float inv_n) {
    __shared__ float warp_sums[4];
    int i = blockIdx.x * blockDim.x + threadIdx.x;

    float viol = 0.0f;
    if (i < n4) {
        vfloat4 a = ax[i], r = rhs[i];
        vint4 s = sense[i];
        float d, pos, neg;
        d = a.x - r.x; pos = fmaxf(d, 0.f); neg = fmaxf(-d, 0.f);
        viol += (s.x == 1) ? pos : (s.x == 2) ? neg : (s.x == 3) ? (pos + neg) : 0.f;
        d = a.y - r.y; pos = fmaxf(d, 0.f); neg = fmaxf(-d, 0.f);
        viol += (s.y == 1) ? pos : (s.y == 2) ? neg : (s.y == 3) ? (pos + neg) : 0.f;
        d = a.z - r.z; pos = fmaxf(d, 0.f); neg = fmaxf(-d, 0.f);
        viol += (s.z == 1) ? pos : (s.z == 2) ? neg : (s.z == 3) ? (pos + neg) : 0.f;
        d = a.w - r.w; pos = fmaxf(d, 0.f); neg = fmaxf(-d, 0.f);
        viol += (s.w == 1) ? pos : (s.w == 2) ? neg : (s.w == 3) ? (pos + neg) : 0.f;
    }

    #pragma unroll
    for (int off = 32; off > 0; off >>= 1) {
        viol += __shfl_down(viol, off, 64);
    }
    int lane = threadIdx.x & 63;
    int wave = threadIdx.x >> 6;
    if (lane == 0) warp_sums[wave] = viol;
    __syncthreads();

    if (threadIdx.x == 0) {
        float s = warp_sums[0] + warp_sums[1] + warp_sums[2] + warp_sums[3];
        atomicAdd(out, s * inv_n);
    }
}

extern "C" void kernel_launch(void* const* d_in, const int* in_sizes, int n_in,
                              void* d_out, int out_size, void* d_ws, size_t ws_size,
                              hipStream_t stream) {
    const float* pred       = (const float*)d_in[0];
    const float* coeff      = (const float*)d_in[1];
    const float* rhs        = (const float*)d_in[2];
    const float* lb         = (const float*)d_in[3];
    const float* ub         = (const float*)d_in[4];
    const int*   constr_idx = (const int*)d_in[5];
    const int*   var_idx    = (const int*)d_in[6];
    const int*   sense      = (const int*)d_in[7];

    const int n_vars    = in_sizes[0];
    const int nnz       = in_sizes[1];
    const int n_constrs = in_sizes[2];

    unsigned short* values_h = (unsigned short*)d_ws;           // n_vars fp16 (2 MB)
    float*          ax       = (float*)((char*)d_ws + (size_t)n_vars * sizeof(unsigned short));
    float*          out      = (float*)d_out;

    const int BLK = 256;

    int n4v = n_vars / 4, n4c = n_constrs / 4;
    int n4max = (n4v > n4c) ? n4v : n4c;
    denorm_zero_kernel<<<(n4max + BLK - 1) / BLK, BLK, 0, stream>>>(
        (const vfloat4*)pred, (const vfloat4*)lb, (const vfloat4*)ub,
        (vhalf4*)values_h, (vfloat4*)ax, out, n4v, n4c);

    int nchunk = (nnz + 31) / 32;
    scatter_kernel<<<(nchunk + BLK - 1) / BLK, BLK, 0, stream>>>(
        (const vfloat4*)coeff, (const vint4*)constr_idx, (const vint4*)var_idx,
        values_h, ax, nnz);

    violation_kernel<<<(n4c + BLK - 1) / BLK, BLK, 0, stream>>>(
        (const vfloat4*)ax, (const vfloat4*)rhs, (const vint4*)sense,
        out, n4c, 1.0f / (float)n_constrs);
}

// Round 6
// 315.294 us; speedup vs baseline: 1.0789x; 1.0789x over previous
//
#include <hip/hip_runtime.h>
#include <hip/hip_fp16.h>

// Clang-native vector types (__builtin_nontemporal_load rejects HIP_vector_type).
typedef float    vfloat4 __attribute__((ext_vector_type(4)));
typedef int      vint4   __attribute__((ext_vector_type(4)));
typedef _Float16 vhalf4  __attribute__((ext_vector_type(4)));

// Bypass gather: agent-scope relaxed atomic load -> sc0, skips L1 (no 64B line
// fill), request+return go straight to the L2 path.
__device__ __forceinline__ float gather_bypass(const unsigned short* tbl, int idx) {
    unsigned short raw = __hip_atomic_load(&tbl[idx], __ATOMIC_RELAXED,
                                           __HIP_MEMORY_SCOPE_AGENT);
    return (float)__builtin_bit_cast(_Float16, raw);
}
// Normal cached gather: goes through L1/TCP MSHR path.
__device__ __forceinline__ float gather_l1(const unsigned short* tbl, int idx) {
    return (float)__builtin_bit_cast(_Float16, tbl[idx]);
}

// Phase 1 (fused): values_h = fp16(pred*(ub-lb)+lb); zero ax; zero out.
__global__ void denorm_zero_kernel(const vfloat4* __restrict__ pred,
                                   const vfloat4* __restrict__ lb,
                                   const vfloat4* __restrict__ ub,
                                   vhalf4* __restrict__ values_h,
                                   vfloat4* __restrict__ ax,
                                   float* __restrict__ out,
                                   int n4v, int n4c) {
    int i = blockIdx.x * blockDim.x + threadIdx.x;
    if (i < n4v) {
        vfloat4 p = pred[i], l = lb[i], u = ub[i];
        vhalf4 h;
        h.x = (_Float16)fmaf(p.x, u.x - l.x, l.x);
        h.y = (_Float16)fmaf(p.y, u.y - l.y, l.y);
        h.z = (_Float16)fmaf(p.z, u.z - l.z, l.z);
        h.w = (_Float16)fmaf(p.w, u.w - l.w, l.w);
        values_h[i] = h;
    }
    if (i < n4c) {
        vfloat4 z = {0.f, 0.f, 0.f, 0.f};
        ax[i] = z;
    }
    if (i == 0) *out = 0.0f;
}

// Phase 2 (R6): TWO far-apart K=16 chunks per thread (chunk t and t+half),
// both wave-coalesced. Both 28-op VMEM bursts issue back-to-back before any
// consume; in-order vmcnt returns mean consume-A (gated on coeffA, issued
// before all of B) overlaps B's in-flight gathers via counted waits. Per-wave
// in-flight VMEM doubles 28->56 WITHOUT the R5 spill: peak liveness ~110 VGPR
// and NO __launch_bounds__ (R5's 128-cap made the compiler spill to scratch
// at 52 VGPR; unbounded degrades gracefully instead).
// Decisive MLP experiment, take 2: Model W (concurrency-bound) predicts
// 123 -> 90-105us; Model Q (fixed per-CU pending-queue) predicts null.
// Streams stay nontemporal dwordx4 via L2 (R1: L3-direct -39%); gather mix
// 25/75 L1/bypass (R2: insensitive); direct global atomics (R4).
__global__ void scatter_kernel(const vfloat4* __restrict__ coeff,
                               const vint4* __restrict__ cidx,
                               const vint4* __restrict__ vidx,
                               const unsigned short* __restrict__ values,
                               float* __restrict__ ax,
                               int nnz, int halfchunks) {
    const int K = 16;
    long t = (long)blockIdx.x * 256 + threadIdx.x;
    long baseA = t * K;
    long baseB = (t + (long)halfchunks) * K;
    if (baseA >= nnz) return;

    const bool fullA = (baseA + K <= nnz);
    const bool haveB = (baseB < nnz);
    const bool fullB = haveB && (baseB + K <= nnz);

    int csegA[16]; float cfA[16]; float valsA[16];
    int csegB[16]; float cfB[16]; float valsB[16];

    // ---- burst A: vidx, cidx, gathers, coeff (28 VMEM ops) ----
    if (fullA) {
        long b4 = baseA / 4;
        int vix[16];
        #pragma unroll
        for (int j = 0; j < 4; j++) {
            vint4 v = __builtin_nontemporal_load(&vidx[b4 + j]);
            vix[4*j+0] = v.x; vix[4*j+1] = v.y; vix[4*j+2] = v.z; vix[4*j+3] = v.w;
        }
        #pragma unroll
        for (int j = 0; j < 4; j++) {
            vint4 c = __builtin_nontemporal_load(&cidx[b4 + j]);
            csegA[4*j+0] = c.x; csegA[4*j+1] = c.y; csegA[4*j+2] = c.z; csegA[4*j+3] = c.w;
        }
        #pragma unroll
        for (int k = 0; k < 16; k += 4) {
            valsA[k]     = gather_l1(values, vix[k]);
            valsA[k + 1] = gather_bypass(values, vix[k + 1]);
            valsA[k + 2] = gather_bypass(values, vix[k + 2]);
            valsA[k + 3] = gather_bypass(values, vix[k + 3]);
        }
        #pragma unroll
        for (int j = 0; j < 4; j++) {
            vfloat4 f = __builtin_nontemporal_load(&coeff[b4 + j]);
            cfA[4*j+0] = f.x; cfA[4*j+1] = f.y; cfA[4*j+2] = f.z; cfA[4*j+3] = f.w;
        }
    }
    // ---- burst B: same, issued before ANY consume ----
    if (fullB) {
        long b4 = baseB / 4;
        int vix[16];
        #pragma unroll
        for (int j = 0; j < 4; j++) {
            vint4 v = __builtin_nontemporal_load(&vidx[b4 + j]);
            vix[4*j+0] = v.x; vix[4*j+1] = v.y; vix[4*j+2] = v.z; vix[4*j+3] = v.w;
        }
        #pragma unroll
        for (int j = 0; j < 4; j++) {
            vint4 c = __builtin_nontemporal_load(&cidx[b4 + j]);
            csegB[4*j+0] = c.x; csegB[4*j+1] = c.y; csegB[4*j+2] = c.z; csegB[4*j+3] = c.w;
        }
        #pragma unroll
        for (int k = 0; k < 16; k += 4) {
            valsB[k]     = gather_l1(values, vix[k]);
            valsB[k + 1] = gather_bypass(values, vix[k + 1]);
            valsB[k + 2] = gather_bypass(values, vix[k + 2]);
            valsB[k + 3] = gather_bypass(values, vix[k + 3]);
        }
        #pragma unroll
        for (int j = 0; j < 4; j++) {
            vfloat4 f = __builtin_nontemporal_load(&coeff[b4 + j]);
            cfB[4*j+0] = f.x; cfB[4*j+1] = f.y; cfB[4*j+2] = f.z; cfB[4*j+3] = f.w;
        }
    }

    // ---- consume A (counted vmcnt: overlaps B's outstanding gathers) ----
    if (fullA) {
        int cur = csegA[0];
        float acc = cfA[0] * valsA[0];
        #pragma unroll
        for (int k = 1; k < 16; k++) {
            if (csegA[k] == cur) {
                acc = fmaf(cfA[k], valsA[k], acc);
            } else {
                atomicAdd(&ax[cur], acc);
                cur = csegA[k];
                acc = cfA[k] * valsA[k];
            }
        }
        atomicAdd(&ax[cur], acc);
    }
    // ---- consume B ----
    if (fullB) {
        int cur = csegB[0];
        float acc = cfB[0] * valsB[0];
        #pragma unroll
        for (int k = 1; k < 16; k++) {
            if (csegB[k] == cur) {
                acc = fmaf(cfB[k], valsB[k], acc);
            } else {
                atomicAdd(&ax[cur], acc);
                cur = csegB[k];
                acc = cfB[k] * valsB[k];
            }
        }
        atomicAdd(&ax[cur], acc);
    }

    // ---- rare scalar tails (last partial chunk runs to nnz) ----
    if (!fullA) {
        const int* ci = (const int*)cidx;
        const int* vi = (const int*)vidx;
        const float* cf = (const float*)coeff;
        int cur = ci[baseA];
        float acc = cf[baseA] * gather_bypass(values, vi[baseA]);
        for (long k = baseA + 1; k < nnz; k++) {
            int s = ci[k];
            float p = cf[k] * gather_bypass(values, vi[k]);
            if (s == cur) acc += p;
            else { atomicAdd(&ax[cur], acc); cur = s; acc = p; }
        }
        atomicAdd(&ax[cur], acc);
    }
    if (haveB && !fullB) {
        const int* ci = (const int*)cidx;
        const int* vi = (const int*)vidx;
        const float* cf = (const float*)coeff;
        int cur = ci[baseB];
        float acc = cf[baseB] * gather_bypass(values, vi[baseB]);
        for (long k = baseB + 1; k < nnz; k++) {
            int s = ci[k];
            float p = cf[k] * gather_bypass(values, vi[k]);
            if (s == cur) acc += p;
            else { atomicAdd(&ax[cur], acc); cur = s; acc = p; }
        }
        atomicAdd(&ax[cur], acc);
    }
}

// Phase 3: violations by sense (x4 vectorized), block reduce, one atomic.
__global__ void violation_kernel(const vfloat4* __restrict__ ax,
                                 const vfloat4* __restrict__ rhs,
                                 const vint4* __restrict__ sense,
                                 float* __restrict__ out,
                                 int n4, float inv_n) {
    __shared__ float warp_sums[4];
    int i = blockIdx.x * blockDim.x + threadIdx.x;

    float viol = 0.0f;
    if (i < n4) {
        vfloat4 a = ax[i], r = rhs[i];
        vint4 s = sense[i];
        float d, pos, neg;
        d = a.x - r.x; pos = fmaxf(d, 0.f); neg = fmaxf(-d, 0.f);
        viol += (s.x == 1) ? pos : (s.x == 2) ? neg : (s.x == 3) ? (pos + neg) : 0.f;
        d = a.y - r.y; pos = fmaxf(d, 0.f); neg = fmaxf(-d, 0.f);
        viol += (s.y == 1) ? pos : (s.y == 2) ? neg : (s.y == 3) ? (pos + neg) : 0.f;
        d = a.z - r.z; pos = fmaxf(d, 0.f); neg = fmaxf(-d, 0.f);
        viol += (s.z == 1) ? pos : (s.z == 2) ? neg : (s.z == 3) ? (pos + neg) : 0.f;
        d = a.w - r.w; pos = fmaxf(d, 0.f); neg = fmaxf(-d, 0.f);
        viol += (s.w == 1) ? pos : (s.w == 2) ? neg : (s.w == 3) ? (pos + neg) : 0.f;
    }

    #pragma unroll
    for (int off = 32; off > 0; off >>= 1) {
        viol += __shfl_down(viol, off, 64);
    }
    int lane = threadIdx.x & 63;
    int wave = threadIdx.x >> 6;
    if (lane == 0) warp_sums[wave] = viol;
    __syncthreads();

    if (threadIdx.x == 0) {
        float s = warp_sums[0] + warp_sums[1] + warp_sums[2] + warp_sums[3];
        atomicAdd(out, s * inv_n);
    }
}

extern "C" void kernel_launch(void* const* d_in, const int* in_sizes, int n_in,
                              void* d_out, int out_size, void* d_ws, size_t ws_size,
                              hipStream_t stream) {
    const float* pred       = (const float*)d_in[0];
    const float* coeff      = (const float*)d_in[1];
    const float* rhs        = (const float*)d_in[2];
    const float* lb         = (const float*)d_in[3];
    const float* ub         = (const float*)d_in[4];
    const int*   constr_idx = (const int*)d_in[5];
    const int*   var_idx    = (const int*)d_in[6];
    const int*   sense      = (const int*)d_in[7];

    const int n_vars    = in_sizes[0];
    const int nnz       = in_sizes[1];
    const int n_constrs = in_sizes[2];

    unsigned short* values_h = (unsigned short*)d_ws;           // n_vars fp16 (2 MB)
    float*          ax       = (float*)((char*)d_ws + (size_t)n_vars * sizeof(unsigned short));
    float*          out      = (float*)d_out;

    const int BLK = 256;

    int n4v = n_vars / 4, n4c = n_constrs / 4;
    int n4max = (n4v > n4c) ? n4v : n4c;
    denorm_zero_kernel<<<(n4max + BLK - 1) / BLK, BLK, 0, stream>>>(
        (const vfloat4*)pred, (const vfloat4*)lb, (const vfloat4*)ub,
        (vhalf4*)values_h, (vfloat4*)ax, out, n4v, n4c);

    int nchunk = (nnz + 15) / 16;
    int halfchunks = (nchunk + 1) / 2;
    scatter_kernel<<<(halfchunks + BLK - 1) / BLK, BLK, 0, stream>>>(
        (const vfloat4*)coeff, (const vint4*)constr_idx, (const vint4*)var_idx,
        values_h, ax, nnz, halfchunks);

    violation_kernel<<<(n4c + BLK - 1) / BLK, BLK, 0, stream>>>(
        (const vfloat4*)ax, (const vfloat4*)rhs, (const vint4*)sense,
        out, n4c, 1.0f / (float)n_constrs);
}

// Round 7
// 308.609 us; speedup vs baseline: 1.1023x; 1.0217x over previous
//
#include <hip/hip_runtime.h>
#include <hip/hip_fp16.h>

// Clang-native vector types (__builtin_nontemporal_load rejects HIP_vector_type).
typedef float    vfloat4 __attribute__((ext_vector_type(4)));
typedef int      vint4   __attribute__((ext_vector_type(4)));
typedef _Float16 vhalf4  __attribute__((ext_vector_type(4)));

// R7: gathers now load the ALIGNED DWORD containing the fp16 entry and select
// the half in VALU. Tests whether sub-dword (2B) divergent loads pay a 2x
// penalty in the shared request pipe (TA/return path). Table and request
// count identical; only access width/alignment changes.

// Bypass gather: agent-scope relaxed atomic load -> sc0, skips L1 (no 64B
// line fill), request+return go straight to the L2 path. Dword-aligned.
__device__ __forceinline__ float gather_bypass(const unsigned short* tbl, int idx) {
    const unsigned* t32 = (const unsigned*)tbl;
    unsigned raw = __hip_atomic_load(&t32[idx >> 1], __ATOMIC_RELAXED,
                                     __HIP_MEMORY_SCOPE_AGENT);
    unsigned short h = (idx & 1) ? (unsigned short)(raw >> 16) : (unsigned short)raw;
    return (float)__builtin_bit_cast(_Float16, h);
}
// Normal cached gather: goes through L1/TCP MSHR path. Dword-aligned.
__device__ __forceinline__ float gather_l1(const unsigned short* tbl, int idx) {
    const unsigned* t32 = (const unsigned*)tbl;
    unsigned raw = t32[idx >> 1];
    unsigned short h = (idx & 1) ? (unsigned short)(raw >> 16) : (unsigned short)raw;
    return (float)__builtin_bit_cast(_Float16, h);
}

// Phase 1 (fused): values_h = fp16(pred*(ub-lb)+lb); zero ax; zero out.
__global__ void denorm_zero_kernel(const vfloat4* __restrict__ pred,
                                   const vfloat4* __restrict__ lb,
                                   const vfloat4* __restrict__ ub,
                                   vhalf4* __restrict__ values_h,
                                   vfloat4* __restrict__ ax,
                                   float* __restrict__ out,
                                   int n4v, int n4c) {
    int i = blockIdx.x * blockDim.x + threadIdx.x;
    if (i < n4v) {
        vfloat4 p = pred[i], l = lb[i], u = ub[i];
        vhalf4 h;
        h.x = (_Float16)fmaf(p.x, u.x - l.x, l.x);
        h.y = (_Float16)fmaf(p.y, u.y - l.y, l.y);
        h.z = (_Float16)fmaf(p.z, u.z - l.z, l.z);
        h.w = (_Float16)fmaf(p.w, u.w - l.w, l.w);
        values_h[i] = h;
    }
    if (i < n4c) {
        vfloat4 z = {0.f, 0.f, 0.f, 0.f};
        ax[i] = z;
    }
    if (i == 0) *out = 0.0f;
}

// Phase 2: thread-coarsened segmented sum (K=16), DIRECT global atomics
// (R4 structure — the 123us reference). Streams nontemporal dwordx4 via L2
// (R1: L3-direct -39%); gather mix 25/75 L1/bypass (R2: insensitive);
// no __launch_bounds__ (R5: the 128-cap caused a spill cliff).
// Evidence so far: shared-resource service wall (R4 vs R6: x0.6 concurrency
// -> only x1.12 time). R7 tests the width attribute of the requests.
__global__ void scatter_kernel(const vfloat4* __restrict__ coeff,
                               const vint4* __restrict__ cidx,
                               const vint4* __restrict__ vidx,
                               const unsigned short* __restrict__ values,
                               float* __restrict__ ax,
                               int nnz) {
    const int K = 16;
    long base = ((long)blockIdx.x * 256 + threadIdx.x) * K;
    if (base >= nnz) return;

    if (base + K <= nnz) {
        long b4 = base / 4;
        int cseg[16]; int vix[16]; float cf[16]; float vals[16];
        // vidx first: the gathers depend on it, start that wait earliest.
        #pragma unroll
        for (int j = 0; j < 4; j++) {
            vint4 v = __builtin_nontemporal_load(&vidx[b4 + j]);
            vix[4*j+0] = v.x; vix[4*j+1] = v.y; vix[4*j+2] = v.z; vix[4*j+3] = v.w;
        }
        #pragma unroll
        for (int j = 0; j < 4; j++) {
            vint4 c = __builtin_nontemporal_load(&cidx[b4 + j]);
            cseg[4*j+0] = c.x; cseg[4*j+1] = c.y; cseg[4*j+2] = c.z; cseg[4*j+3] = c.w;
        }
        // 25/75 L1/bypass gather mix, dword-aligned loads.
        #pragma unroll
        for (int k = 0; k < 16; k += 4) {
            vals[k]     = gather_l1(values, vix[k]);         // L1/MSHR path
            vals[k + 1] = gather_bypass(values, vix[k + 1]); // sc0/L2 path
            vals[k + 2] = gather_bypass(values, vix[k + 2]);
            vals[k + 3] = gather_bypass(values, vix[k + 3]);
        }
        #pragma unroll
        for (int j = 0; j < 4; j++) {
            vfloat4 f = __builtin_nontemporal_load(&coeff[b4 + j]);
            cf[4*j+0] = f.x; cf[4*j+1] = f.y; cf[4*j+2] = f.z; cf[4*j+3] = f.w;
        }

        int cur = cseg[0];
        float acc = cf[0] * vals[0];
        #pragma unroll
        for (int k = 1; k < 16; k++) {
            if (cseg[k] == cur) {
                acc = fmaf(cf[k], vals[k], acc);
            } else {
                atomicAdd(&ax[cur], acc);
                cur = cseg[k];
                acc = cf[k] * vals[k];
            }
        }
        atomicAdd(&ax[cur], acc);
    } else {
        // Tail chunk: scalar.
        const int* ci = (const int*)cidx;
        const int* vi = (const int*)vidx;
        const float* cf = (const float*)coeff;
        int cur = ci[base];
        float acc = cf[base] * gather_bypass(values, vi[base]);
        for (long k = base + 1; k < nnz; k++) {
            int s = ci[k];
            float p = cf[k] * gather_bypass(values, vi[k]);
            if (s == cur) acc += p;
            else {
                atomicAdd(&ax[cur], acc);
                cur = s; acc = p;
            }
        }
        atomicAdd(&ax[cur], acc);
    }
}

// Phase 3: violations by sense (x4 vectorized), block reduce, one atomic.
__global__ void violation_kernel(const vfloat4* __restrict__ ax,
                                 const vfloat4* __restrict__ rhs,
                                 const vint4* __restrict__ sense,
                                 float* __restrict__ out,
                                 int n4, float inv_n) {
    __shared__ float warp_sums[4];
    int i = blockIdx.x * blockDim.x + threadIdx.x;

    float viol = 0.0f;
    if (i < n4) {
        vfloat4 a = ax[i], r = rhs[i];
        vint4 s = sense[i];
        float d, pos, neg;
        d = a.x - r.x; pos = fmaxf(d, 0.f); neg = fmaxf(-d, 0.f);
        viol += (s.x == 1) ? pos : (s.x == 2) ? neg : (s.x == 3) ? (pos + neg) : 0.f;
        d = a.y - r.y; pos = fmaxf(d, 0.f); neg = fmaxf(-d, 0.f);
        viol += (s.y == 1) ? pos : (s.y == 2) ? neg : (s.y == 3) ? (pos + neg) : 0.f;
        d = a.z - r.z; pos = fmaxf(d, 0.f); neg = fmaxf(-d, 0.f);
        viol += (s.z == 1) ? pos : (s.z == 2) ? neg : (s.z == 3) ? (pos + neg) : 0.f;
        d = a.w - r.w; pos = fmaxf(d, 0.f); neg = fmaxf(-d, 0.f);
        viol += (s.w == 1) ? pos : (s.w == 2) ? neg : (s.w == 3) ? (pos + neg) : 0.f;
    }

    #pragma unroll
    for (int off = 32; off > 0; off >>= 1) {
        viol += __shfl_down(viol, off, 64);
    }
    int lane = threadIdx.x & 63;
    int wave = threadIdx.x >> 6;
    if (lane == 0) warp_sums[wave] = viol;
    __syncthreads();

    if (threadIdx.x == 0) {
        float s = warp_sums[0] + warp_sums[1] + warp_sums[2] + warp_sums[3];
        atomicAdd(out, s * inv_n);
    }
}

extern "C" void kernel_launch(void* const* d_in, const int* in_sizes, int n_in,
                              void* d_out, int out_size, void* d_ws, size_t ws_size,
                              hipStream_t stream) {
    const float* pred       = (const float*)d_in[0];
    const float* coeff      = (const float*)d_in[1];
    const float* rhs        = (const float*)d_in[2];
    const float* lb         = (const float*)d_in[3];
    const float* ub         = (const float*)d_in[4];
    const int*   constr_idx = (const int*)d_in[5];
    const int*   var_idx    = (const int*)d_in[6];
    const int*   sense      = (const int*)d_in[7];

    const int n_vars    = in_sizes[0];
    const int nnz       = in_sizes[1];
    const int n_constrs = in_sizes[2];

    unsigned short* values_h = (unsigned short*)d_ws;           // n_vars fp16 (2 MB)
    float*          ax       = (float*)((char*)d_ws + (size_t)n_vars * sizeof(unsigned short));
    float*          out      = (float*)d_out;

    const int BLK = 256;

    int n4v = n_vars / 4, n4c = n_constrs / 4;
    int n4max = (n4v > n4c) ? n4v : n4c;
    denorm_zero_kernel<<<(n4max + BLK - 1) / BLK, BLK, 0, stream>>>(
        (const vfloat4*)pred, (const vfloat4*)lb, (const vfloat4*)ub,
        (vhalf4*)values_h, (vfloat4*)ax, out, n4v, n4c);

    int nchunk = (nnz + 15) / 16;
    scatter_kernel<<<(nchunk + BLK - 1) / BLK, BLK, 0, stream>>>(
        (const vfloat4*)coeff, (const vint4*)constr_idx, (const vint4*)var_idx,
        values_h, ax, nnz);

    violation_kernel<<<(n4c + BLK - 1) / BLK, BLK, 0, stream>>>(
        (const vfloat4*)ax, (const vfloat4*)rhs, (const vint4*)sense,
        out, n4c, 1.0f / (float)n_constrs);
}

// Round 8
// 301.093 us; speedup vs baseline: 1.1298x; 1.0250x over previous
//
#include <hip/hip_runtime.h>
#include <hip/hip_fp16.h>

// Clang-native vector types (__builtin_nontemporal_load rejects HIP_vector_type).
typedef float    vfloat4 __attribute__((ext_vector_type(4)));
typedef int      vint4   __attribute__((ext_vector_type(4)));
typedef _Float16 vhalf4  __attribute__((ext_vector_type(4)));

// Bypass gather: agent-scope relaxed atomic load -> sc0, skips L1 (no 64B
// line fill), request+return go straight to the L2 path. 2-byte access:
// R7 proved dword-aligned gathers are ~6% SLOWER, so native fp16 loads stay.
__device__ __forceinline__ float gather_bypass(const unsigned short* tbl, int idx) {
    unsigned short raw = __hip_atomic_load(&tbl[idx], __ATOMIC_RELAXED,
                                           __HIP_MEMORY_SCOPE_AGENT);
    return (float)__builtin_bit_cast(_Float16, raw);
}

// Phase 1 (fused): values_h = fp16(pred*(ub-lb)+lb); zero ax; zero out.
__global__ void denorm_zero_kernel(const vfloat4* __restrict__ pred,
                                   const vfloat4* __restrict__ lb,
                                   const vfloat4* __restrict__ ub,
                                   vhalf4* __restrict__ values_h,
                                   vfloat4* __restrict__ ax,
                                   float* __restrict__ out,
                                   int n4v, int n4c) {
    int i = blockIdx.x * blockDim.x + threadIdx.x;
    if (i < n4v) {
        vfloat4 p = pred[i], l = lb[i], u = ub[i];
        vhalf4 h;
        h.x = (_Float16)fmaf(p.x, u.x - l.x, l.x);
        h.y = (_Float16)fmaf(p.y, u.y - l.y, l.y);
        h.z = (_Float16)fmaf(p.z, u.z - l.z, l.z);
        h.w = (_Float16)fmaf(p.w, u.w - l.w, l.w);
        values_h[i] = h;
    }
    if (i < n4c) {
        vfloat4 z = {0.f, 0.f, 0.f, 0.f};
        ax[i] = z;
    }
    if (i == 0) *out = 0.0f;
}

// Phase 2: thread-coarsened segmented sum (K=16), DIRECT global atomics —
// the R4 123us structure, reverted from R7's dword experiment.
// CHANGE (R8): gathers are 100% sc0-bypass (was 25% L1 / 75% bypass). The
// L1-path hit rate is ~1.6% (2MB table vs 32KB L1) and each miss dragged a
// 64B line fill (~256MB TCC->TCP total); eliminating the path removes that
// traffic. R2 (50/50 vs 25/75 null) predicts this is neutral — it rides
// along with the mandatory revert.
// Evidence ledger: shared divergent-request service wall ~0.21 lanes/cyc/CU;
// insensitive to path mix (R2), width (R7), weakly sensitive to concurrency
// (R6: x0.6 -> x1.12 time); streams must stay in L2 (R1: L3-direct -39%);
// no __launch_bounds__ (R5: 128-cap spill cliff).
__global__ void scatter_kernel(const vfloat4* __restrict__ coeff,
                               const vint4* __restrict__ cidx,
                               const vint4* __restrict__ vidx,
                               const unsigned short* __restrict__ values,
                               float* __restrict__ ax,
                               int nnz) {
    const int K = 16;
    long base = ((long)blockIdx.x * 256 + threadIdx.x) * K;
    if (base >= nnz) return;

    if (base + K <= nnz) {
        long b4 = base / 4;
        int cseg[16]; int vix[16]; float cf[16]; float vals[16];
        // vidx first: the gathers depend on it, start that wait earliest.
        #pragma unroll
        for (int j = 0; j < 4; j++) {
            vint4 v = __builtin_nontemporal_load(&vidx[b4 + j]);
            vix[4*j+0] = v.x; vix[4*j+1] = v.y; vix[4*j+2] = v.z; vix[4*j+3] = v.w;
        }
        #pragma unroll
        for (int j = 0; j < 4; j++) {
            vint4 c = __builtin_nontemporal_load(&cidx[b4 + j]);
            cseg[4*j+0] = c.x; cseg[4*j+1] = c.y; cseg[4*j+2] = c.z; cseg[4*j+3] = c.w;
        }
        // 100% sc0-bypass gathers.
        #pragma unroll
        for (int k = 0; k < 16; k++) {
            vals[k] = gather_bypass(values, vix[k]);
        }
        #pragma unroll
        for (int j = 0; j < 4; j++) {
            vfloat4 f = __builtin_nontemporal_load(&coeff[b4 + j]);
            cf[4*j+0] = f.x; cf[4*j+1] = f.y; cf[4*j+2] = f.z; cf[4*j+3] = f.w;
        }

        int cur = cseg[0];
        float acc = cf[0] * vals[0];
        #pragma unroll
        for (int k = 1; k < 16; k++) {
            if (cseg[k] == cur) {
                acc = fmaf(cf[k], vals[k], acc);
            } else {
                atomicAdd(&ax[cur], acc);
                cur = cseg[k];
                acc = cf[k] * vals[k];
            }
        }
        atomicAdd(&ax[cur], acc);
    } else {
        // Tail chunk: scalar.
        const int* ci = (const int*)cidx;
        const int* vi = (const int*)vidx;
        const float* cf = (const float*)coeff;
        int cur = ci[base];
        float acc = cf[base] * gather_bypass(values, vi[base]);
        for (long k = base + 1; k < nnz; k++) {
            int s = ci[k];
            float p = cf[k] * gather_bypass(values, vi[k]);
            if (s == cur) acc += p;
            else {
                atomicAdd(&ax[cur], acc);
                cur = s; acc = p;
            }
        }
        atomicAdd(&ax[cur], acc);
    }
}

// Phase 3: violations by sense (x4 vectorized), block reduce, one atomic.
__global__ void violation_kernel(const vfloat4* __restrict__ ax,
                                 const vfloat4* __restrict__ rhs,
                                 const vint4* __restrict__ sense,
                                 float* __restrict__ out,
                                 int n4, float inv_n) {
    __shared__ float warp_sums[4];
    int i = blockIdx.x * blockDim.x + threadIdx.x;

    float viol = 0.0f;
    if (i < n4) {
        vfloat4 a = ax[i], r = rhs[i];
        vint4 s = sense[i];
        float d, pos, neg;
        d = a.x - r.x; pos = fmaxf(d, 0.f); neg = fmaxf(-d, 0.f);
        viol += (s.x == 1) ? pos : (s.x == 2) ? neg : (s.x == 3) ? (pos + neg) : 0.f;
        d = a.y - r.y; pos = fmaxf(d, 0.f); neg = fmaxf(-d, 0.f);
        viol += (s.y == 1) ? pos : (s.y == 2) ? neg : (s.y == 3) ? (pos + neg) : 0.f;
        d = a.z - r.z; pos = fmaxf(d, 0.f); neg = fmaxf(-d, 0.f);
        viol += (s.z == 1) ? pos : (s.z == 2) ? neg : (s.z == 3) ? (pos + neg) : 0.f;
        d = a.w - r.w; pos = fmaxf(d, 0.f); neg = fmaxf(-d, 0.f);
        viol += (s.w == 1) ? pos : (s.w == 2) ? neg : (s.w == 3) ? (pos + neg) : 0.f;
    }

    #pragma unroll
    for (int off = 32; off > 0; off >>= 1) {
        viol += __shfl_down(viol, off, 64);
    }
    int lane = threadIdx.x & 63;
    int wave = threadIdx.x >> 6;
    if (lane == 0) warp_sums[wave] = viol;
    __syncthreads();

    if (threadIdx.x == 0) {
        float s = warp_sums[0] + warp_sums[1] + warp_sums[2] + warp_sums[3];
        atomicAdd(out, s * inv_n);
    }
}

extern "C" void kernel_launch(void* const* d_in, const int* in_sizes, int n_in,
                              void* d_out, int out_size, void* d_ws, size_t ws_size,
                              hipStream_t stream) {
    const float* pred       = (const float*)d_in[0];
    const float* coeff      = (const float*)d_in[1];
    const float* rhs        = (const float*)d_in[2];
    const float* lb         = (const float*)d_in[3];
    const float* ub         = (const float*)d_in[4];
    const int*   constr_idx = (const int*)d_in[5];
    const int*   var_idx    = (const int*)d_in[6];
    const int*   sense      = (const int*)d_in[7];

    const int n_vars    = in_sizes[0];
    const int nnz       = in_sizes[1];
    const int n_constrs = in_sizes[2];

    unsigned short* values_h = (unsigned short*)d_ws;           // n_vars fp16 (2 MB)
    float*          ax       = (float*)((char*)d_ws + (size_t)n_vars * sizeof(unsigned short));
    float*          out      = (float*)d_out;

    const int BLK = 256;

    int n4v = n_vars / 4, n4c = n_constrs / 4;
    int n4max = (n4v > n4c) ? n4v : n4c;
    denorm_zero_kernel<<<(n4max + BLK - 1) / BLK, BLK, 0, stream>>>(
        (const vfloat4*)pred, (const vfloat4*)lb, (const vfloat4*)ub,
        (vhalf4*)values_h, (vfloat4*)ax, out, n4v, n4c);

    int nchunk = (nnz + 15) / 16;
    scatter_kernel<<<(nchunk + BLK - 1) / BLK, BLK, 0, stream>>>(
        (const vfloat4*)coeff, (const vint4*)constr_idx, (const vint4*)var_idx,
        values_h, ax, nnz);

    violation_kernel<<<(n4c + BLK - 1) / BLK, BLK, 0, stream>>>(
        (const vfloat4*)ax, (const vfloat4*)rhs, (const vint4*)sense,
        out, n4c, 1.0f / (float)n_constrs);
}